// Round 13
// baseline (235.449 us; speedup 1.0000x reference)
//
#include <hip/hip_runtime.h>

// out[b,p,c] = sum_s (x[b,s,c]-x[b,S-1,c]) * W[c,p,s] + bias[c,p] + x[b,S-1,c]
//   1) xpose: x'(c,b,s) = bf16(x[b,s,c]-x[b,S-1,c]) into d_ws (86 MB), linear.
//   2) gemm R13: block = 256 thr / 4 waves / 64 b / 1 c-plane, grid 1000
//      (500 c x 2 b-halves, XCD-remapped so (c,0),(c,1) share W via L2).
//      A register-resident (21 x short8 = 84 VGPR). W streamed contiguously
//      p-tile-wise (16 rows x 672 s fp32 -> bf16 LDS dbuf). 3 blocks/CU
//      co-resident -> independent-block TLP hides stage latency (r3-r5 regime).

typedef __attribute__((ext_vector_type(8))) short short8;   // 8 bf16
typedef __attribute__((ext_vector_type(4))) float floatx4;  // MFMA C/D

namespace {
constexpr int Bn = 128, Sn = 672, Pn = 168, Cn = 500;
constexpr int XQ = Bn * Sn;           // ushorts per c-plane of x'
constexpr int TC = 64, TS = 96, TROW = TS + 12;   // xpose tile
constexpr int NS  = Sn / 32;          // 21 s-chunks (MFMA K=32)
constexpr int NPT = 11;               // p-tiles of 16 (last half-masked)
constexpr int WROW = 676;             // LDS W row pitch (672 + 4 pad ushorts)
}

__device__ __forceinline__ unsigned short f2bf(float f) {  // RTNE f32->bf16
  unsigned int u = __builtin_bit_cast(unsigned int, f);
  u += 0x7fffu + ((u >> 16) & 1u);
  return (unsigned short)(u >> 16);
}

// ---------------------------------------------------------------- xpose ----
__global__ __launch_bounds__(256)
void xpose_kernel(const float* __restrict__ x, unsigned short* __restrict__ xq) {
  __shared__ unsigned short T[TC][TROW];
  const int b  = blockIdx.x;
  const int s0 = blockIdx.y * TS;
  const int c0 = blockIdx.z * TC;
  const int t  = threadIdx.x;

  #pragma unroll
  for (int i = 0; i < 6; ++i) {
    const int idx = t + i * 256;       // 96 s-rows x 16 c-quads
    const int sr  = idx >> 4;
    const int cq  = (idx & 15) * 4;
    int c = c0 + cq;
    if (c > Cn - 4) c = Cn - 4;        // clamp (16B-aligned); dup writes identical
    const int rel = c - c0;
    const float4 xv = *(const float4*)&x[(size_t)(b * Sn + s0 + sr) * Cn + c];
    const float4 xl = *(const float4*)&x[(size_t)(b * Sn + (Sn - 1)) * Cn + c];
    T[rel + 0][sr] = f2bf(xv.x - xl.x);
    T[rel + 1][sr] = f2bf(xv.y - xl.y);
    T[rel + 2][sr] = f2bf(xv.z - xl.z);
    T[rel + 3][sr] = f2bf(xv.w - xl.w);
  }
  __syncthreads();
  #pragma unroll
  for (int i = 0; i < 6; ++i) {
    const int idx = t + i * 256;       // 64 c-rows x 24 s-quads
    const int cr  = idx / 24;
    const int sq  = (idx % 24) * 4;
    const int c   = c0 + cr;
    if (c >= Cn) continue;
    const ushort4 v = *(const ushort4*)&T[cr][sq];
    *(ushort4*)&xq[(size_t)c * XQ + b * Sn + s0 + sq] = v;
  }
}

// ----------------------------------------------------------------- gemm ----
// Barrier waits LDS only; global-load waits are compiler-counted per register.
#define BAR_LGKM() asm volatile("s_waitcnt lgkmcnt(0)\n\ts_barrier" ::: "memory")

__global__ __launch_bounds__(256, 3)   // VGPR cap 170; live ~140 -> no spill; 3 blk/CU
void gemm_kernel(const unsigned short* __restrict__ xq, const float* __restrict__ W,
                 const float* __restrict__ bias, const float* __restrict__ x,
                 float* __restrict__ out) {
  __shared__ unsigned short Wl[2][16 * WROW];   // 2 x 21.1 KB bf16, padded rows
  __shared__ float xl_l[64];
  __shared__ float bi_l[Pn];

  // bijective XCD remap (1000 = 8*125): consecutive wids on one XCD.
  const int bid = blockIdx.x;
  const int wid = (bid & 7) * 125 + (bid >> 3);
  const int c0  = wid >> 1;            // 0..499
  const int bh  = wid & 1;             // b-half; (c,0),(c,1) adjacent -> W L2-shared

  const int tid  = threadIdx.x;
  const int lane = tid & 63;
  const int wv   = tid >> 6;           // wave owns b in [bh*64 + wv*16, +16)
  const int r16  = lane & 15;
  const int kg   = lane >> 4;

  const float* Wc = W + (size_t)c0 * Pn * Sn;   // this c-plane (451.6 KB contiguous)

  // ---- stage one p-tile (16 rows x 672 s fp32 -> bf16 LDS) ----
  auto stageW = [&](int pt, int buf) {
    #pragma unroll
    for (int k = 0; k < 11; ++k) {
      if (k == 10 && tid >= 128) continue;     // 2688 = 10*256 + 128
      const int idx  = tid + 256 * k;          // (row,col4) row-major, width 168
      const int row  = idx / 168;              // 0..15
      const int colw = idx * 4 - row * 672;    // col in floats
      int p = pt * 16 + row;
      if (p > Pn - 1) p = Pn - 1;              // tail tile clamp (stores masked)
      const float4 w = *(const float4*)(Wc + (size_t)p * Sn + colw);
      ushort4 u;
      u.x = f2bf(w.x); u.y = f2bf(w.y); u.z = f2bf(w.z); u.w = f2bf(w.w);
      *(ushort4*)&Wl[buf][row * WROW + colw] = u;
    }
  };

  // ---- prologue: stage W(0); xlast/bias; A preload (21 x short8) ----
  stageW(0, 0);
  if (tid < 64) {
    const int b = bh * 64 + tid;
    xl_l[tid] = x[((size_t)b * Sn + (Sn - 1)) * Cn + c0];
  } else if (tid < 64 + Pn) {
    bi_l[tid - 64] = bias[(size_t)c0 * Pn + (tid - 64)];
  }
  const unsigned short* aBase =
      xq + (size_t)c0 * XQ + (size_t)(bh * 64 + wv * 16 + r16) * Sn + kg * 8;
  short8 aR[NS];                        // 84 VGPR, resident for whole kernel
  #pragma unroll
  for (int s = 0; s < NS; ++s) aR[s] = *(const short8*)(aBase + s * 32);
  BAR_LGKM();

  // ---- main loop over p-tiles ----
  #pragma unroll 1
  for (int pt = 0; pt < NPT; ++pt) {
    const int buf = pt & 1;
    if (pt + 1 < NPT) stageW(pt + 1, buf ^ 1);   // issue next tile early

    floatx4 acc = (floatx4){0.f, 0.f, 0.f, 0.f};
    const int rdb = r16 * WROW + kg * 8;
    #pragma unroll
    for (int s = 0; s < NS; ++s) {
      const short8 wf = *(const short8*)&Wl[buf][rdb + s * 32];
      acc = __builtin_amdgcn_mfma_f32_16x16x32_bf16(aR[s], wf, acc, 0, 0, 0);
    }

    // per-tile epilogue: D col = r16 (=p), row = kg*4 + r (=b offset)
    const int p = pt * 16 + r16;
    if (p < Pn) {
      const float bi = bi_l[p];
      #pragma unroll
      for (int r = 0; r < 4; ++r) {
        const int bl = wv * 16 + kg * 4 + r;
        out[((size_t)(bh * 64 + bl) * Pn + p) * Cn + c0] = acc[r] + bi + xl_l[bl];
      }
    }

    if (pt + 1 < NPT) BAR_LGKM();       // next tile staged; no vmcnt drain
  }
}

extern "C" void kernel_launch(void* const* d_in, const int* in_sizes, int n_in,
                              void* d_out, int out_size, void* d_ws, size_t ws_size,
                              hipStream_t stream) {
  (void)in_sizes; (void)n_in; (void)out_size; (void)ws_size;  // needs ws >= 86,016,000 B
  const float* x  = (const float*)d_in[0];
  const float* W  = (const float*)d_in[1];
  const float* bv = (const float*)d_in[2];
  float* out = (float*)d_out;
  unsigned short* xq = (unsigned short*)d_ws;

  hipLaunchKernelGGL(xpose_kernel, dim3(Bn, Sn / TS, (Cn + TC - 1) / TC), dim3(256), 0, stream,
                     x, xq);
  hipLaunchKernelGGL(gemm_kernel, dim3(1000), dim3(256), 0, stream,
                     xq, W, bv, x, out);
}

// Round 14
// 150.728 us; speedup vs baseline: 1.5621x; 1.5621x over previous
//
#include <hip/hip_runtime.h>

// out[b,p,c] = sum_s (x[b,s,c]-x[b,S-1,c]) * W[c,p,s] + bias[c,p] + x[b,S-1,c]
//   1) xpose: x'(c,b,s) = bf16(x[b,s,c]-x[b,S-1,c]) into d_ws (86 MB), linear.
//   2) gemm R14 = r12 shape + r7 depth-2 schedule: block = ONE c-plane,
//      512 thr / 8 waves, A register-resident (21 x short8 = 84 VGPR),
//      W streamed contiguously (11 p-tiles x 43 KB) through TWO static reg
//      sets -> bf16 LDS dbuf. Loads for tile pt+2 issue during compute(pt):
//      counted vmcnt wait sees a full tile period of slack -> HBM latency
//      hidden. Barriers wait lgkmcnt only. (512,2) = proven no-spill config.

typedef __attribute__((ext_vector_type(8))) short short8;   // 8 bf16
typedef __attribute__((ext_vector_type(4))) float floatx4;  // MFMA C/D

namespace {
constexpr int Bn = 128, Sn = 672, Pn = 168, Cn = 500;
constexpr int XQ = Bn * Sn;           // ushorts per c-plane of x'
constexpr int TC = 64, TS = 96, TROW = TS + 12;   // xpose tile
constexpr int NS  = Sn / 32;          // 21 s-chunks (MFMA K=32)
constexpr int NPT = 11;               // p-tiles of 16 (last half-masked)
constexpr int WROW = 680;             // LDS W row pitch in ushorts (672+8 pad)
}

__device__ __forceinline__ unsigned short f2bf(float f) {  // RTNE f32->bf16
  unsigned int u = __builtin_bit_cast(unsigned int, f);
  u += 0x7fffu + ((u >> 16) & 1u);
  return (unsigned short)(u >> 16);
}

// ---------------------------------------------------------------- xpose ----
__global__ __launch_bounds__(256)
void xpose_kernel(const float* __restrict__ x, unsigned short* __restrict__ xq) {
  __shared__ unsigned short T[TC][TROW];
  const int b  = blockIdx.x;
  const int s0 = blockIdx.y * TS;
  const int c0 = blockIdx.z * TC;
  const int t  = threadIdx.x;

  #pragma unroll
  for (int i = 0; i < 6; ++i) {
    const int idx = t + i * 256;       // 96 s-rows x 16 c-quads
    const int sr  = idx >> 4;
    const int cq  = (idx & 15) * 4;
    int c = c0 + cq;
    if (c > Cn - 4) c = Cn - 4;        // clamp (16B-aligned); dup writes identical
    const int rel = c - c0;
    const float4 xv = *(const float4*)&x[(size_t)(b * Sn + s0 + sr) * Cn + c];
    const float4 xl = *(const float4*)&x[(size_t)(b * Sn + (Sn - 1)) * Cn + c];
    T[rel + 0][sr] = f2bf(xv.x - xl.x);
    T[rel + 1][sr] = f2bf(xv.y - xl.y);
    T[rel + 2][sr] = f2bf(xv.z - xl.z);
    T[rel + 3][sr] = f2bf(xv.w - xl.w);
  }
  __syncthreads();
  #pragma unroll
  for (int i = 0; i < 6; ++i) {
    const int idx = t + i * 256;       // 64 c-rows x 24 s-quads
    const int cr  = idx / 24;
    const int sq  = (idx % 24) * 4;
    const int c   = c0 + cr;
    if (c >= Cn) continue;
    const ushort4 v = *(const ushort4*)&T[cr][sq];
    *(ushort4*)&xq[(size_t)c * XQ + b * Sn + s0 + sq] = v;
  }
}

// ----------------------------------------------------------------- gemm ----
// Barrier waits LDS only; global-load waits are compiler-counted per register.
#define BAR_LGKM() asm volatile("s_waitcnt lgkmcnt(0)\n\ts_barrier" ::: "memory")

__global__ __launch_bounds__(512, 2)   // proven no-spill config (r10/r12)
void gemm_kernel(const unsigned short* __restrict__ xq, const float* __restrict__ W,
                 const float* __restrict__ bias, const float* __restrict__ x,
                 float* __restrict__ out) {
  __shared__ unsigned short Wl[2][16 * WROW];   // 2 x 21.25 KB bf16, padded rows
  __shared__ float xl_l[Bn];
  __shared__ float bi_l[Pn];

  // bijective XCD remap: consecutive c-planes co-run on one XCD (write merge)
  const int bid = blockIdx.x;
  const int xcd = bid & 7, sub = bid >> 3;
  const int c0  = xcd * 62 + (xcd < 4 ? xcd : 4) + sub;   // 0..499

  const int tid  = threadIdx.x;
  const int lane = tid & 63;
  const int wv   = tid >> 6;           // wave owns b in [16*wv, 16*wv+16)
  const int r16  = lane & 15;
  const int kg   = lane >> 4;

  // ---- W staging descriptors: 2688 float4 per p-tile, 6 per thread ----
  int wrow[6], wcol[6];
  #pragma unroll
  for (int k = 0; k < 6; ++k) {
    const int f = tid + 512 * k;
    wrow[k] = f / 168;
    wcol[k] = f % 168;
  }
  const bool w5 = tid < 128;           // 2688 = 5*512 + 128

  float4 w0[6], w1[6];                 // two static prefetch sets (rule #20: const idx)

  auto loadW0 = [&](int pt) {
    #pragma unroll
    for (int k = 0; k < 6; ++k) {
      if (k == 5 && !w5) continue;
      int row = pt * 16 + wrow[k];
      if (row > Pn - 1) row = Pn - 1;
      w0[k] = *(const float4*)&W[((size_t)c0 * Pn + row) * Sn + wcol[k] * 4];
    }
  };
  auto loadW1 = [&](int pt) {
    #pragma unroll
    for (int k = 0; k < 6; ++k) {
      if (k == 5 && !w5) continue;
      int row = pt * 16 + wrow[k];
      if (row > Pn - 1) row = Pn - 1;
      w1[k] = *(const float4*)&W[((size_t)c0 * Pn + row) * Sn + wcol[k] * 4];
    }
  };
  auto writeW0 = [&](int buf) {        // counted vmcnt wait on w0 only
    #pragma unroll
    for (int k = 0; k < 6; ++k) {
      if (k == 5 && !w5) continue;
      ushort4 u;
      u.x = f2bf(w0[k].x); u.y = f2bf(w0[k].y);
      u.z = f2bf(w0[k].z); u.w = f2bf(w0[k].w);
      *(ushort4*)&Wl[buf][wrow[k] * WROW + wcol[k] * 4] = u;
    }
  };
  auto writeW1 = [&](int buf) {
    #pragma unroll
    for (int k = 0; k < 6; ++k) {
      if (k == 5 && !w5) continue;
      ushort4 u;
      u.x = f2bf(w1[k].x); u.y = f2bf(w1[k].y);
      u.z = f2bf(w1[k].z); u.w = f2bf(w1[k].w);
      *(ushort4*)&Wl[buf][wrow[k] * WROW + wcol[k] * 4] = u;
    }
  };

  // ---- compute + per-tile epilogue ----
  const unsigned short* aBase = xq + (size_t)c0 * XQ + (wv * 16 + r16) * Sn + kg * 8;
  short8 aR[NS];                        // 84 VGPR, resident for whole kernel
  auto tile = [&](int pt, int buf) {
    floatx4 acc = (floatx4){0.f, 0.f, 0.f, 0.f};
    const int rdb = r16 * WROW + kg * 8;
    #pragma unroll
    for (int s = 0; s < NS; ++s) {
      const short8 wf = *(const short8*)&Wl[buf][rdb + s * 32];
      acc = __builtin_amdgcn_mfma_f32_16x16x32_bf16(aR[s], wf, acc, 0, 0, 0);
    }
    const int p = pt * 16 + r16;        // D col = r16 (=p), row = kg*4 + r
    if (p < Pn) {
      const float bi = bi_l[p];
      #pragma unroll
      for (int r = 0; r < 4; ++r) {
        const int b = wv * 16 + kg * 4 + r;
        out[((size_t)b * Pn + p) * Cn + c0] = acc[r] + bi + xl_l[b];
      }
    }
  };

  // ---- prologue ----
  loadW0(0);                            // tile 0 -> set0
  loadW1(1);                            // tile 1 -> set1
  if (tid < Bn) xl_l[tid] = x[((size_t)tid * Sn + (Sn - 1)) * Cn + c0];
  else if (tid < Bn + Pn) bi_l[tid - Bn] = bias[(size_t)c0 * Pn + (tid - Bn)];
  #pragma unroll
  for (int s = 0; s < NS; ++s) aR[s] = *(const short8*)(aBase + s * 32);
  writeW0(0);                           // waits w0 only; w1 + aR stay in flight
  BAR_LGKM();

  // ---- main loop: pairs (even=buf0/set0, odd=buf1/set1), NPT = 11 ----
  #pragma unroll 1
  for (int jj = 0; jj < NPT - 1; jj += 2) {
    // pt = jj (even): compute buf0; stage tile jj+1 (set1 -> buf1); refill set0
    writeW1(1);                         // waits w1: issued >= 1 tile period ago
    loadW0(jj + 2);                     // jj+2 <= 10 always (jj <= 8)
    tile(jj, 0);
    BAR_LGKM();
    // pt = jj+1 (odd): compute buf1; stage tile jj+2 (set0 -> buf0); refill set1
    writeW0(0);
    if (jj + 3 < NPT) loadW1(jj + 3);
    tile(jj + 1, 1);
    BAR_LGKM();
  }
  tile(NPT - 1, 0);                     // pt = 10 (even, buf0)
}

extern "C" void kernel_launch(void* const* d_in, const int* in_sizes, int n_in,
                              void* d_out, int out_size, void* d_ws, size_t ws_size,
                              hipStream_t stream) {
  (void)in_sizes; (void)n_in; (void)out_size; (void)ws_size;  // needs ws >= 86,016,000 B
  const float* x  = (const float*)d_in[0];
  const float* W  = (const float*)d_in[1];
  const float* bv = (const float*)d_in[2];
  float* out = (float*)d_out;
  unsigned short* xq = (unsigned short*)d_ws;

  hipLaunchKernelGGL(xpose_kernel, dim3(Bn, Sn / TS, (Cn + TC - 1) / TC), dim3(256), 0, stream,
                     x, xq);
  hipLaunchKernelGGL(gemm_kernel, dim3(Cn), dim3(512), 0, stream,
                     xq, W, bv, x, out);
}